// Round 6
// baseline (209.850 us; speedup 1.0000x reference)
//
#include <hip/hip_runtime.h>
#include <cstdint>
#include <cstddef>

namespace {

constexpr int Bn   = 8;
constexpr int Cc   = 128;
constexpr int Hh   = 56;
constexpr int Ww   = 56;
constexpr int OUTC = 128;
constexpr int NTAP = 9;
constexpr int HW   = 3136;
constexpr int NPOS = Bn * HW;      // 25088
constexpr int KDIM = 1152;         // Cc*NTAP

constexpr int PT   = 32;           // K2 positions per block
constexpr int CCH  = 32;           // K2 channels per chunk (4 chunks)
constexpr int KC   = CCH * NTAP;   // 288
constexpr int LROW = 296;          // ushort row stride: 592 B, 16B-aligned

typedef __attribute__((ext_vector_type(8))) short  short8v;
typedef __attribute__((ext_vector_type(4))) short  short4v;
typedef __attribute__((ext_vector_type(4))) float  float4v;

__device__ __forceinline__ unsigned short f2bf(float f) {
    union { float f; uint32_t u; } v; v.f = f;
    const uint32_t u = v.u;
    return (unsigned short)((u + 0x7fffu + ((u >> 16) & 1u)) >> 16);  // RNE
}

// ---------------------------------------------------------------------------
// Prep: (a) cwb: conv weights bf16, k' = cc*288 + n*32 + cl
//       (b) owp: offset weights fp32 permuted to [c][m*9+tap] (contiguous/c)
//       (c) xt32: x transposed to [b][ij][c] fp32 (LDS-tiled, both sides
//           coalesced)
// ---------------------------------------------------------------------------
__global__ __launch_bounds__(256) void prep_kernel(
        const float* __restrict__ cw, const float* __restrict__ ow,
        const float* __restrict__ x, unsigned short* __restrict__ cwb,
        float* __restrict__ owp, float* __restrict__ xt32) {
    const int blk = blockIdx.x;
    const int t = threadIdx.x;
    if (blk < 576) {                               // 128*1152 elems
        const int i = blk * 256 + t;
        const int o = i / KDIM, k = i % KDIM;
        const int cc = k / KC, r = k % KC, n = r >> 5, cl = r & 31;
        cwb[i] = f2bf(cw[o * KDIM + (cc * CCH + cl) * NTAP + n]);
        return;
    }
    if (blk < 657) {                               // owp: 128*162 = 20736 elems
        const int i = (blk - 576) * 256 + t;
        const int c = i / 162, r = i % 162;        // r = m*9+tap
        owp[i] = ow[(r / 9) * KDIM + c * NTAP + (r % 9)];
        return;
    }
    // transpose: 392 blocks, 64 pos x 128 ch each
    __shared__ float tile[64 * 129];
    const int blk2 = blk - 657;
    const int b = blk2 & 7;
    const int ijb = (blk2 >> 3) * 64;
    const float* xb = x + (size_t)b * Cc * HW + ijb;
    for (int e = t; e < 64 * Cc; e += 256) {       // read: lanes = consecutive pos
        const int pos = e & 63, c = e >> 6;
        tile[pos * 129 + c] = xb[(size_t)c * HW + pos];
    }
    __syncthreads();
    float* xr = xt32 + ((size_t)b * HW + ijb) * Cc;
    for (int e = t; e < 64 * Cc; e += 256) {       // write: lanes = consecutive c
        const int pos = e >> 7, c = e & 127;
        xr[(size_t)pos * Cc + c] = tile[pos * 129 + c];
    }
}

// ---------------------------------------------------------------------------
// K1: offset conv + p. BIT-IDENTICAL FP order to the R4/R5-verified pbuf:
// per-(pos,m) partials over 16-c slices (taps ky*3+kx ascending), 8-way
// LDS reduce g=0..7 ascending, +bias, base+s.
// Weights from owp: per cc-iteration one contiguous 648B uniform run ->
// s_load_dwordx16 batches. x taps via GLOBAL loads (vmcnt; no lgkm mixing).
// ---------------------------------------------------------------------------
__global__ __launch_bounds__(512) void offset_p_kernel(
        const float* __restrict__ x, const float* __restrict__ owp,
        const float* __restrict__ ob, float* __restrict__ pbuf) {
    __shared__ float red[8][64 * 18];              // 36.9 KB

    const int t    = threadIdx.x;
    const int lane = t & 63;
    const int g    = __builtin_amdgcn_readfirstlane(t >> 6);   // wave-uniform
    const int blk  = blockIdx.x;
    const int b    = blk & 7;                      // XCD affinity
    const int ijb  = (blk >> 3) * 64;
    const int ij   = ijb + lane;
    const int i    = ij / Ww, j = ij % Ww;
    const float* xb = x + (size_t)b * Cc * HW;

    float acc[18];
#pragma unroll
    for (int m = 0; m < 18; ++m) acc[m] = 0.f;

    for (int cc = 0; cc < 16; ++cc) {
        const int c = g * 16 + cc;
        const float* xc = xb + (size_t)c * HW;
        float xv[9];
#pragma unroll
        for (int ky = 0; ky < 3; ++ky) {
            const int y = i + ky - 1;
            const bool yv = (unsigned)y < (unsigned)Hh;
#pragma unroll
            for (int kx = 0; kx < 3; ++kx) {
                const int xx = j + kx - 1;
                xv[ky * 3 + kx] = (yv && (unsigned)xx < (unsigned)Ww) ? xc[y * Ww + xx] : 0.f;
            }
        }
        const float* wp = owp + c * 162;           // uniform, CONTIGUOUS
#pragma unroll
        for (int m = 0; m < 18; ++m) {
#pragma unroll
            for (int tap = 0; tap < 9; ++tap)
                acc[m] = fmaf(wp[m * 9 + tap], xv[tap], acc[m]);
        }
    }

#pragma unroll
    for (int m = 0; m < 18; ++m) red[g][lane * 18 + m] = acc[m];
    __syncthreads();

    for (int e = t; e < 64 * 18; e += 512) {
        const int lpe = e / 18, m = e % 18;
        float s = 0.f;
#pragma unroll
        for (int gg = 0; gg < 8; ++gg) s += red[gg][e];
        s += ob[m];
        const int ije = ijb + lpe;
        const float base = (m < 9) ? (float)(ije / Ww + m / 3)
                                   : (float)(ije % Ww + (m - 9) % 3);
        pbuf[(size_t)(b * 18 + m) * HW + ije] = base + s;
    }
}

// ---------------------------------------------------------------------------
// K2: branchless 4-corner sampling from fp32 channel-last xt32 + MFMA GEMM.
// Exact fp32 trunc-bilinear params once per (pos,tap) into LDS.
// CCH=32 -> 25.3 KB LDS -> 6 blocks/CU. A-frags via single ds_read_b128.
// ---------------------------------------------------------------------------
__global__ __launch_bounds__(256) void deform_mfma_kernel(
        const float* __restrict__ xt32, const unsigned short* __restrict__ cwb,
        const float* __restrict__ pbuf, float* __restrict__ out) {
    __shared__ unsigned short xoffB[PT * LROW];    // 18.5 KB
    __shared__ float4v pgS[PT * NTAP];             // {g2,g3,g0,g1}  4.6 KB
    __shared__ int2    poS[PT * NTAP];             // {o2|o3<<16, o0|o1<<16} 2.3 KB

    const int t    = threadIdx.x;
    const int lane = t & 63;
    const int mm   = lane & 15, quad = lane >> 4;
    const int wv   = t >> 6;
    const int lp   = t & 31, sl = t >> 5;          // staging: pos, 4-ch slice
    const int blk  = blockIdx.x;
    const int b    = blk & 7;                      // XCD affinity
    const int ijb  = (blk >> 3) * PT;
    const float* xtb = xt32 + (size_t)b * HW * Cc;

    // ---- params: exact fp32, once per (pos,tap); e = n*32 + pos ----
    for (int e = t; e < PT * NTAP; e += 256) {
        const int n = e >> 5, lpe = e & 31;
        const int ij = ijb + lpe;
        const float py = pbuf[(size_t)(b * 18 + n) * HW + ij];
        const float px = pbuf[(size_t)(b * 18 + 9 + n) * HW + ij];
        const float q0y = floorf(py), q0x = floorf(px);
        const float lty = fminf(fmaxf(q0y, 0.f), 57.f);
        const float ltx = fminf(fmaxf(q0x, 0.f), 57.f);
        const float rby = fminf(fmaxf(q0y + 1.f, 0.f), 57.f);
        const float rbx = fminf(fmaxf(q0x + 1.f, 0.f), 57.f);
        const float pyc = fminf(fmaxf(py, 0.f), 57.f);
        const float pxc = fminf(fmaxf(px, 0.f), 57.f);
        float g0 = (1.f - (pyc - lty)) * truncf(1.f - (pxc - ltx));   // lt
        float g1 = (1.f - (rby - pyc)) * truncf(1.f - (rbx - pxc));   // rb
        float g2 = (1.f - (pyc - lty)) * (1.f - (rbx - pxc));         // lb (lty,rbx)
        float g3 = (1.f - (rby - pyc)) * (1.f - (pxc - ltx));         // rt (rby,ltx)
        const int y0 = (int)lty - 1, x0 = (int)ltx - 1;
        const int y1 = (int)rby - 1, x1 = (int)rbx - 1;
        const bool v0y = (unsigned)y0 < (unsigned)Hh, v0x = (unsigned)x0 < (unsigned)Ww;
        const bool v1y = (unsigned)y1 < (unsigned)Hh, v1x = (unsigned)x1 < (unsigned)Ww;
        int o0 = y0 * Ww + x0, o1 = y1 * Ww + x1, o2 = y0 * Ww + x1, o3 = y1 * Ww + x0;
        if (!(v0y && v0x)) { o0 = 0; g0 = 0.f; }
        if (!(v1y && v1x)) { o1 = 0; g1 = 0.f; }
        if (!(v0y && v1x)) { o2 = 0; g2 = 0.f; }
        if (!(v1y && v0x)) { o3 = 0; g3 = 0.f; }
        pgS[e] = (float4v){ g2, g3, g0, g1 };
        poS[e] = make_int2((o2 & 0xffff) | (o3 << 16), (o0 & 0xffff) | (o1 << 16));
    }

    float4v acc[2][2] = { { {0.f,0.f,0.f,0.f}, {0.f,0.f,0.f,0.f} },
                          { {0.f,0.f,0.f,0.f}, {0.f,0.f,0.f,0.f} } };
    __syncthreads();

    for (int cc = 0; cc < 4; ++cc) {
        if (cc) __syncthreads();
        // ---- branchless staging: 9 taps x 4 corners x 4ch (float4 gathers) ----
        const int cbase = cc * CCH + sl * 4;
#pragma unroll
        for (int n = 0; n < 9; ++n) {
            const float4v G = pgS[n * 32 + lp];
            const int2  O = poS[n * 32 + lp];
            const float4v a2 = *(const float4v*)(xtb + (size_t)(O.x & 0xffff) * Cc + cbase);
            const float4v a3 = *(const float4v*)(xtb + (size_t)((O.x >> 16) & 0xffff) * Cc + cbase);
            const float4v a0 = *(const float4v*)(xtb + (size_t)(O.y & 0xffff) * Cc + cbase);
            const float4v a1 = *(const float4v*)(xtb + (size_t)((O.y >> 16) & 0xffff) * Cc + cbase);
            short4v pk;
#pragma unroll
            for (int u = 0; u < 4; ++u) {
                float v = G.x * a2[u];
                v = fmaf(G.y, a3[u], v);
                v = fmaf(G.z, a0[u], v);
                v = fmaf(G.w, a1[u], v);
                pk[u] = (short)f2bf(v);
            }
            *(short4v*)&xoffB[lp * LROW + n * CCH + sl * 4] = pk;   // 8B-aligned
        }
        __syncthreads();

        // ---- MFMA GEMM: 9 ks-steps, B straight from L2, A via ds_read_b128 ----
        const unsigned short* bw0 = cwb + (size_t)(wv * 32 + mm) * KDIM + cc * KC;
        const unsigned short* bw1 = bw0 + 16 * KDIM;
        const unsigned short* ap0 = &xoffB[mm * LROW + quad * 8];
#pragma unroll 3
        for (int ks = 0; ks < KC / 32; ++ks) {
            const int kl = ks * 32;
            const short8v b0 = *(const short8v*)(bw0 + kl + quad * 8);
            const short8v b1 = *(const short8v*)(bw1 + kl + quad * 8);
#pragma unroll
            for (int pt = 0; pt < 2; ++pt) {
                const short8v a = *(const short8v*)(ap0 + pt * 16 * LROW + kl); // 16B-aligned
                acc[pt][0] = __builtin_amdgcn_mfma_f32_16x16x32_bf16(a, b0, acc[pt][0], 0, 0, 0);
                acc[pt][1] = __builtin_amdgcn_mfma_f32_16x16x32_bf16(a, b1, acc[pt][1], 0, 0, 0);
            }
        }
    }

    // ---- epilogue (layout verified R2/R4/R5) ----
    float* ob0 = out + (size_t)(b * OUTC + wv * 32 + mm) * HW + ijb + quad * 4;
#pragma unroll
    for (int pt = 0; pt < 2; ++pt) {
        *(float4v*)(ob0 + pt * 16) = acc[pt][0];
        *(float4v*)(ob0 + (size_t)16 * HW + pt * 16) = acc[pt][1];
    }
}

}  // namespace

extern "C" void kernel_launch(void* const* d_in, const int* in_sizes, int n_in,
                              void* d_out, int out_size, void* d_ws, size_t ws_size,
                              hipStream_t stream) {
    const float* x  = (const float*)d_in[0];   // (8,128,56,56)
    const float* ow = (const float*)d_in[1];   // (18,128,3,3)
    const float* ob = (const float*)d_in[2];   // (18,)
    const float* cw = (const float*)d_in[3];   // (128,128,3,3)
    float* out = (float*)d_out;                // (8,128,56,56)

    char* wsp = (char*)d_ws;
    float* pbuf = (float*)wsp;                                   // 1,806,336 B
    unsigned short* cwb = (unsigned short*)(wsp + 1806336);      //   294,912 B
    float* owp  = (float*)(wsp + 1806336 + 294912);              //    82,944 B
    float* xt32 = (float*)(wsp + 1806336 + 294912 + 82944);      // 12,845,056 B

    prep_kernel<<<576 + 81 + 392, 256, 0, stream>>>(cw, ow, x, cwb, owp, xt32);
    offset_p_kernel<<<NPOS / 64, 512, 0, stream>>>(x, owp, ob, pbuf);
    deform_mfma_kernel<<<NPOS / PT, 256, 0, stream>>>(xt32, cwb, pbuf, out);
}